// Round 19
// baseline (36.270 us; speedup 1.0000x reference)
//
#include <hip/hip_runtime.h>
#include <hip/hip_bf16.h>
#include <cmath>

// Round 19: r18 verbatim, register budget forced under the 128-VGPR
// occupancy cliff:
//   - waves_per_eu(4,4): hard 128-reg cap -> 4 waves/SIMD -> all 4
//     blocks/CU co-resident (single generation; no straggler 4th block).
//     r17/r18's (3,4) allowed up to 168 regs -> likely 3 waves/SIMD ->
//     25% of blocks ran as a second generation (~the missing 10us).
//   - Prefetch depth 2 buffer sets (32 fewer VGPRs than r17's 4 sets);
//     128 B/lane still in flight during TAIL.
//   - Unchanged: split prep; swapped MFMA (A=x, B=W^T); double-buffered
//     wave-private LDS patch (WAR closed); lgkmcnt(0)+sched_barrier
//     before TAIL read (RAW closed); cvt_pk bf16 pack; rcp-tanh.

typedef __attribute__((ext_vector_type(8))) short bf16x8;
typedef __attribute__((ext_vector_type(4))) float f32x4;

// ---- prep kernel: verbatim round-10 (validated rounds 10-18) ----
__global__ __launch_bounds__(256) void qprep_kernel(
    const float* __restrict__ qw,   // [3][4][2]
    float* __restrict__ A_out)      // [81][4]
{
  __shared__ float sre[16][17];
  __shared__ float sim[16][17];
  __shared__ float M[4][16][16];
  const int tid = threadIdx.x;
  const int col = tid >> 4;
  const int u   = tid & 15;

  sre[col][u] = (u == col) ? 1.0f : 0.0f;
  sim[col][u] = 0.0f;
  __syncthreads();

#pragma unroll
  for (int l = 0; l < 3; ++l) {
#pragma unroll
    for (int w = 0; w < 4; ++w) {
      const int mask = 8 >> w;     // wire 0 = MSB
      float sh, ch, sh2, ch2;
      __sincosf(0.5f * qw[(l * 4 + w) * 2 + 0], &sh, &ch);    // RY
      __sincosf(0.5f * qw[(l * 4 + w) * 2 + 1], &sh2, &ch2);  // RZ
      const int ua = u & ~mask, ub = u | mask;
      const float ar = sre[col][ua], ai = sim[col][ua];
      const float br = sre[col][ub], bi = sim[col][ub];
      __syncthreads();
      float nr, ni;
      if (u & mask) { nr = sh * ar + ch * br; ni = sh * ai + ch * bi; }
      else          { nr = ch * ar - sh * br; ni = ch * ai - sh * bi; }
      float rr, ri;
      if (u & mask) { rr = ch2 * nr - sh2 * ni; ri = ch2 * ni + sh2 * nr; }
      else          { rr = ch2 * nr + sh2 * ni; ri = ch2 * ni - sh2 * nr; }
      sre[col][u] = rr; sim[col][u] = ri;
      __syncthreads();
    }
    int src = u;
    if (src & 1) src ^= 8;
    if (src & 2) src ^= 1;
    if (src & 4) src ^= 2;
    if (src & 8) src ^= 4;
    const float pr = sre[col][src], pi = sim[col][src];
    __syncthreads();
    sre[col][u] = pr; sim[col][u] = pi;
    __syncthreads();
  }

  for (int idx = tid; idx < 1024; idx += 256) {
    const int w = idx >> 8, s = (idx >> 4) & 15, t = idx & 15;
    const int mask = 8 >> w;
    float acc = 0.0f;
#pragma unroll
    for (int uu = 0; uu < 16; ++uu) {
      const float z = (uu & mask) ? -1.0f : 1.0f;
      acc += z * (sre[s][uu] * sre[t][uu] + sim[s][uu] * sim[t][uu]);
    }
    M[w][s][t] = acc;
  }
  __syncthreads();

  for (int idx = tid; idx < 324; idx += 256) {
    const int w = idx & 3, pq = idx >> 2;
    const int p = pq / 9, q = pq % 9;
    const int i0 = p / 3, i1 = p % 3, i2 = q / 3, i3 = q % 3;
    float acc = 0.0f;
#pragma unroll
    for (int comb = 0; comb < 16; ++comb) {
      int s = 0, t = 0;
      float coef = 0.0625f;
      int j;
      j = (comb >> 3) & 1; s |= j << 3; t |= ((i0 == 2) ? (j ^ 1) : j) << 3; if (i0 == 1 && j) coef = -coef;
      j = (comb >> 2) & 1; s |= j << 2; t |= ((i1 == 2) ? (j ^ 1) : j) << 2; if (i1 == 1 && j) coef = -coef;
      j = (comb >> 1) & 1; s |= j << 1; t |= ((i2 == 2) ? (j ^ 1) : j) << 1; if (i2 == 1 && j) coef = -coef;
      j = comb & 1;        s |= j;      t |= ((i3 == 2) ? (j ^ 1) : j);      if (i3 == 1 && j) coef = -coef;
      acc = fmaf(coef, M[w][s][t], acc);
    }
    A_out[idx] = acc;   // layout [pq*4 + w]
  }
}

// pack 8 floats -> bf16x8 via compiler casts (emits v_cvt_pk_bf16_f32)
__device__ __forceinline__ bf16x8 pack8(const float4 va, const float4 vb) {
  union { bf16x8 v; __hip_bfloat16 h[8]; } u;
  u.h[0] = __float2bfloat16(va.x); u.h[1] = __float2bfloat16(va.y);
  u.h[2] = __float2bfloat16(va.z); u.h[3] = __float2bfloat16(va.w);
  u.h[4] = __float2bfloat16(vb.x); u.h[5] = __float2bfloat16(vb.y);
  u.h[6] = __float2bfloat16(vb.z); u.h[7] = __float2bfloat16(vb.w);
  return u.v;
}

// fast tanh: 1 - 2*rcp(e^{2a}+1); rcp is v_rcp_f32 (err ~1ulp, thr 2e-2)
__device__ __forceinline__ float ftanh(float a) {
  return 1.0f - 2.0f * __builtin_amdgcn_rcpf(__expf(2.0f * a) + 1.0f);
}

// load subtile S (16 rows) of tile base R0 into 4 named float4 regs
#define LDSUB(V0, V1, V2, V3, R0, S) {                                      \
  const float* rp_ = x + ((R0) + (size_t)((S) * 16 + arow)) * 64 + kgrp * 8;\
  V0 = *reinterpret_cast<const float4*>(rp_);                               \
  V1 = *reinterpret_cast<const float4*>(rp_ + 4);                           \
  V2 = *reinterpret_cast<const float4*>(rp_ + 32);                          \
  V3 = *reinterpret_cast<const float4*>(rp_ + 36); }

// cvt(pk) + 2x MFMA (A=x, B=W^T) + scalar scatter into LDS buf LB
#define DOMFMA(V0, V1, V2, V3, M, LB) {                                     \
  const bf16x8 af0_ = pack8(V0, V1);                                        \
  const bf16x8 af1_ = pack8(V2, V3);                                        \
  f32x4 acc_ = __builtin_amdgcn_mfma_f32_16x16x32_bf16(af0_, wf0, zero, 0, 0, 0); \
  acc_ = __builtin_amdgcn_mfma_f32_16x16x32_bf16(af1_, wf1, acc_, 0, 0, 0); \
  if (arow < 4) {                                                           \
    _Pragma("unroll")                                                       \
    for (int r_ = 0; r_ < 4; ++r_)                                          \
      myld[(LB) * 256 + ((M) * 16 + kgrp * 4 + r_) * 4 + arow] = acc_[r_];  \
  } }

// tail for one 64-row tile at base R0, reading LDS buffer LB
#define TAIL(R0, LB) {                                                      \
  asm volatile("s_waitcnt lgkmcnt(0)" ::: "memory");                        \
  __builtin_amdgcn_sched_barrier(0);                                        \
  const float4 ang =                                                        \
      *reinterpret_cast<const float4*>(&myld[(LB) * 256 + lane * 4]);       \
  const float t0 = ftanh(ang.x + bp[0]);                                    \
  const float t1 = ftanh(ang.y + bp[1]);                                    \
  const float t2 = ftanh(ang.z + bp[2]);                                    \
  const float t3 = ftanh(ang.w + bp[3]);                                    \
  float c0, s0, c1, s1, c2, s2, c3, s3;                                     \
  __sincosf(t0, &s0, &c0); __sincosf(t1, &s1, &c1);                         \
  __sincosf(t2, &s2, &c2); __sincosf(t3, &s3, &c3);                         \
  const float g[9] = {1.f, c1, s1, c0, c0 * c1, c0 * s1,                    \
                      s0, s0 * c1, s0 * s1};                                \
  const float h[9] = {1.f, c3, s3, c2, c2 * c3, c2 * s3,                    \
                      s2, s2 * c3, s2 * s3};                                \
  float e0 = 0.f, e1 = 0.f, e2 = 0.f, e3 = 0.f;                             \
  _Pragma("unroll")                                                         \
  for (int p_ = 0; p_ < 9; ++p_) {                                          \
    _Pragma("unroll")                                                       \
    for (int q_ = 0; q_ < 9; ++q_) {                                        \
      const float4 a4 = Aws[p_ * 9 + q_];                                   \
      const float tt = g[p_] * h[q_];                                       \
      e0 = fmaf(a4.x, tt, e0); e1 = fmaf(a4.y, tt, e1);                     \
      e2 = fmaf(a4.z, tt, e2); e3 = fmaf(a4.w, tt, e3);                     \
    }                                                                       \
  }                                                                         \
  reinterpret_cast<float4*>(out)[(R0) + lane] =                             \
      make_float4(e0, e1, e2, e3);                                          \
  asm volatile("" ::: "memory"); }

__global__ __launch_bounds__(256)
__attribute__((amdgpu_waves_per_eu(4, 4)))   // HARD 128-VGPR cap: 4 waves/SIMD
void qmain_kernel(
    const float* __restrict__ x,     // [B][64]
    const float* __restrict__ Wp,    // [4][64]
    const float* __restrict__ bp,    // [4]
    const float4* __restrict__ Aws,  // [81] float4 (d_ws)
    float* __restrict__ out)         // [B][4]
{
  __shared__ alignas(16) float wlds[4][2][256];   // 2KB/wave, double-buffered

  const int tid  = threadIdx.x;
  const int lane = tid & 63;
  const int wid  = tid >> 6;
  const int arow = lane & 15;        // x-row in subtile / C column (qubit)
  const int kgrp = lane >> 4;        // k-group
  float* myld = &wlds[wid][0][0];

  const size_t wrow0 = ((size_t)blockIdx.x * 4 + wid) * 128;  // 2 tiles

  // B fragment: W^T, cols 0..3 real, 4..15 zero (r13-r18 proven)
  bf16x8 wf0, wf1;
#pragma unroll
  for (int j = 0; j < 8; ++j) {
    if (arow < 4) {
      union { short s; __hip_bfloat16 h; } u0, u1;
      u0.h = __float2bfloat16(Wp[arow * 64 + 0  + kgrp * 8 + j]);
      u1.h = __float2bfloat16(Wp[arow * 64 + 32 + kgrp * 8 + j]);
      wf0[j] = u0.s; wf1[j] = u1.s;
    } else {
      wf0[j] = 0; wf1[j] = 0;
    }
  }
  const f32x4 zero = {0.f, 0.f, 0.f, 0.f};

  const size_t r0 = wrow0;            // tile 0
  const size_t r1 = wrow0 + 64;       // tile 1

  // two named buffer sets (depth 2): 32 VGPRs under r17's four sets
  float4 a0, a1, a2, a3, b0, b1, b2, b3;

  // ---- tile 0: rolling depth-2; 2 subtiles of tile 1 in flight at TAIL ----
  LDSUB(a0, a1, a2, a3, r0, 0);
  LDSUB(b0, b1, b2, b3, r0, 1);
  DOMFMA(a0, a1, a2, a3, 0, 0); LDSUB(a0, a1, a2, a3, r0, 2);
  DOMFMA(b0, b1, b2, b3, 1, 0); LDSUB(b0, b1, b2, b3, r0, 3);
  DOMFMA(a0, a1, a2, a3, 2, 0); LDSUB(a0, a1, a2, a3, r1, 0);
  DOMFMA(b0, b1, b2, b3, 3, 0); LDSUB(b0, b1, b2, b3, r1, 1);

  TAIL(r0, 0);   // reads buffer 0; tile-1 writes go to buffer 1 (no WAR)

  // ---- tile 1 ----
  DOMFMA(a0, a1, a2, a3, 0, 1); LDSUB(a0, a1, a2, a3, r1, 2);
  DOMFMA(b0, b1, b2, b3, 1, 1); LDSUB(b0, b1, b2, b3, r1, 3);
  DOMFMA(a0, a1, a2, a3, 2, 1);
  DOMFMA(b0, b1, b2, b3, 3, 1);

  TAIL(r1, 1);
}

extern "C" void kernel_launch(void* const* d_in, const int* in_sizes, int n_in,
                              void* d_out, int out_size, void* d_ws, size_t ws_size,
                              hipStream_t stream) {
  const float* x  = (const float*)d_in[0];
  const float* Wp = (const float*)d_in[1];
  const float* bp = (const float*)d_in[2];
  const float* qw = (const float*)d_in[3];
  float* out = (float*)d_out;
  float* A = (float*)d_ws;   // 324 floats
  (void)n_in; (void)out_size; (void)ws_size;

  qprep_kernel<<<1, 256, 0, stream>>>(qw, A);

  const int B = in_sizes[0] / 64;   // 524288 rows
  qmain_kernel<<<B / 512, 256, 0, stream>>>(x, Wp, bp,
                                            (const float4*)A, out);
}

// Round 20
// 34.672 us; speedup vs baseline: 1.0461x; 1.0461x over previous
//
#include <hip/hip_runtime.h>
#include <hip/hip_bf16.h>
#include <cmath>

// Round 20: contiguous-global-load staging.
//   Evidence: r15's pure-stream qgemv (no tail/LDS/barriers) still ran
//   ~36us -> the SEGMENTED fragment load pattern (32 half-used lines per
//   b128 instr) is the limiter, plausibly via line-granular TA queue
//   occupancy. Fix: lane l loads subtile_base + l*16B (1KB fully-coalesced
//   per instr, 16 whole lines), redistribute via wave-private XOR-swizzled
//   LDS (word ^= (row&7)<<2; conflict-free both sides, 8 lanes/quad).
//   Pipeline: 3 transit reg sets, ISSUE-early/WRITE-late, depth-3 subtiles
//   in flight; zero s_barrier (wave-internal in-order DS); r17-proven
//   MFMA + scatter + TAIL (lgkmcnt(0)+sched_barrier before reads).

typedef __attribute__((ext_vector_type(8))) short bf16x8;
typedef __attribute__((ext_vector_type(4))) float f32x4;

// ---- prep kernel: verbatim round-10 (validated rounds 10-19) ----
__global__ __launch_bounds__(256) void qprep_kernel(
    const float* __restrict__ qw,   // [3][4][2]
    float* __restrict__ A_out)      // [81][4]
{
  __shared__ float sre[16][17];
  __shared__ float sim[16][17];
  __shared__ float M[4][16][16];
  const int tid = threadIdx.x;
  const int col = tid >> 4;
  const int u   = tid & 15;

  sre[col][u] = (u == col) ? 1.0f : 0.0f;
  sim[col][u] = 0.0f;
  __syncthreads();

#pragma unroll
  for (int l = 0; l < 3; ++l) {
#pragma unroll
    for (int w = 0; w < 4; ++w) {
      const int mask = 8 >> w;     // wire 0 = MSB
      float sh, ch, sh2, ch2;
      __sincosf(0.5f * qw[(l * 4 + w) * 2 + 0], &sh, &ch);    // RY
      __sincosf(0.5f * qw[(l * 4 + w) * 2 + 1], &sh2, &ch2);  // RZ
      const int ua = u & ~mask, ub = u | mask;
      const float ar = sre[col][ua], ai = sim[col][ua];
      const float br = sre[col][ub], bi = sim[col][ub];
      __syncthreads();
      float nr, ni;
      if (u & mask) { nr = sh * ar + ch * br; ni = sh * ai + ch * bi; }
      else          { nr = ch * ar - sh * br; ni = ch * ai - sh * bi; }
      float rr, ri;
      if (u & mask) { rr = ch2 * nr - sh2 * ni; ri = ch2 * ni + sh2 * nr; }
      else          { rr = ch2 * nr + sh2 * ni; ri = ch2 * ni - sh2 * nr; }
      sre[col][u] = rr; sim[col][u] = ri;
      __syncthreads();
    }
    int src = u;
    if (src & 1) src ^= 8;
    if (src & 2) src ^= 1;
    if (src & 4) src ^= 2;
    if (src & 8) src ^= 4;
    const float pr = sre[col][src], pi = sim[col][src];
    __syncthreads();
    sre[col][u] = pr; sim[col][u] = pi;
    __syncthreads();
  }

  for (int idx = tid; idx < 1024; idx += 256) {
    const int w = idx >> 8, s = (idx >> 4) & 15, t = idx & 15;
    const int mask = 8 >> w;
    float acc = 0.0f;
#pragma unroll
    for (int uu = 0; uu < 16; ++uu) {
      const float z = (uu & mask) ? -1.0f : 1.0f;
      acc += z * (sre[s][uu] * sre[t][uu] + sim[s][uu] * sim[t][uu]);
    }
    M[w][s][t] = acc;
  }
  __syncthreads();

  for (int idx = tid; idx < 324; idx += 256) {
    const int w = idx & 3, pq = idx >> 2;
    const int p = pq / 9, q = pq % 9;
    const int i0 = p / 3, i1 = p % 3, i2 = q / 3, i3 = q % 3;
    float acc = 0.0f;
#pragma unroll
    for (int comb = 0; comb < 16; ++comb) {
      int s = 0, t = 0;
      float coef = 0.0625f;
      int j;
      j = (comb >> 3) & 1; s |= j << 3; t |= ((i0 == 2) ? (j ^ 1) : j) << 3; if (i0 == 1 && j) coef = -coef;
      j = (comb >> 2) & 1; s |= j << 2; t |= ((i1 == 2) ? (j ^ 1) : j) << 2; if (i1 == 1 && j) coef = -coef;
      j = (comb >> 1) & 1; s |= j << 1; t |= ((i2 == 2) ? (j ^ 1) : j) << 1; if (i2 == 1 && j) coef = -coef;
      j = comb & 1;        s |= j;      t |= ((i3 == 2) ? (j ^ 1) : j);      if (i3 == 1 && j) coef = -coef;
      acc = fmaf(coef, M[w][s][t], acc);
    }
    A_out[idx] = acc;   // layout [pq*4 + w]
  }
}

// pack 8 floats -> bf16x8 via compiler casts (emits v_cvt_pk_bf16_f32)
__device__ __forceinline__ bf16x8 pack8(const float4 va, const float4 vb) {
  union { bf16x8 v; __hip_bfloat16 h[8]; } u;
  u.h[0] = __float2bfloat16(va.x); u.h[1] = __float2bfloat16(va.y);
  u.h[2] = __float2bfloat16(va.z); u.h[3] = __float2bfloat16(va.w);
  u.h[4] = __float2bfloat16(vb.x); u.h[5] = __float2bfloat16(vb.y);
  u.h[6] = __float2bfloat16(vb.z); u.h[7] = __float2bfloat16(vb.w);
  return u.v;
}

// fast tanh: 1 - 2*rcp(e^{2a}+1)
__device__ __forceinline__ float ftanh(float a) {
  return 1.0f - 2.0f * __builtin_amdgcn_rcpf(__expf(2.0f * a) + 1.0f);
}

// ---- ISSUE: 4 fully-contiguous 1KB loads (lane l gets bytes l*16+i*1024
//      of subtile S = rows [S*16, S*16+16) x 256B) ----
#define ISSUE(S, R0, R1, R2, R3) {                                          \
  const float4* g_ = xs4 + (wrow0 + (size_t)((S) * 16)) * 16 + lane;        \
  R0 = g_[0]; R1 = g_[64]; R2 = g_[128]; R3 = g_[192]; }

// ---- WRITE: swizzled ds_write of the 4 pieces into sbuf (S&1) ----
// piece i: linear word = lane*4 + i*256, its x-row = (lane>>4)+4i;
// swizzle word ^= ((row&7)<<2).  wsA/wsB precomputed per lane.
#define WRITE(R0, R1, R2, R3, S) {                                          \
  float* d_ = sb + ((S) & 1) * 1024;                                        \
  *reinterpret_cast<float4*>(d_ + wsA)        = R0;                         \
  *reinterpret_cast<float4*>(d_ + wsB + 256)  = R1;                         \
  *reinterpret_cast<float4*>(d_ + wsA + 512)  = R2;                         \
  *reinterpret_cast<float4*>(d_ + wsB + 768)  = R3; }

// ---- CONSUME: swizzled b128 reads -> pack -> 2 MFMA -> scatter ----
#define CONSUME(S) {                                                        \
  const float* s_ = sb + ((S) & 1) * 1024;                                  \
  const float4 f0 = *reinterpret_cast<const float4*>(s_ + ((cb_ + 0) ^ rw_)); \
  const float4 f1 = *reinterpret_cast<const float4*>(s_ + ((cb_ + 4) ^ rw_)); \
  const float4 f2 = *reinterpret_cast<const float4*>(s_ + ((cb_ + 32) ^ rw_)); \
  const float4 f3 = *reinterpret_cast<const float4*>(s_ + ((cb_ + 36) ^ rw_)); \
  const bf16x8 af0_ = pack8(f0, f1);                                        \
  const bf16x8 af1_ = pack8(f2, f3);                                        \
  f32x4 acc_ = __builtin_amdgcn_mfma_f32_16x16x32_bf16(af0_, wf0, zero, 0, 0, 0); \
  acc_ = __builtin_amdgcn_mfma_f32_16x16x32_bf16(af1_, wf1, acc_, 0, 0, 0); \
  if (arow < 4) {                                                           \
    _Pragma("unroll")                                                       \
    for (int r_ = 0; r_ < 4; ++r_)                                          \
      ap[((((S) & 3) * 16) + kgrp * 4 + r_) * 4 + arow] = acc_[r_];         \
  } }

// ---- TAIL: lane owns row R0+lane; fences close RAW (rule #18) ----
#define TAIL(R0) {                                                          \
  asm volatile("s_waitcnt lgkmcnt(0)" ::: "memory");                        \
  __builtin_amdgcn_sched_barrier(0);                                        \
  const float4 ang = *reinterpret_cast<const float4*>(&ap[lane * 4]);       \
  const float t0 = ftanh(ang.x + bp[0]);                                    \
  const float t1 = ftanh(ang.y + bp[1]);                                    \
  const float t2 = ftanh(ang.z + bp[2]);                                    \
  const float t3 = ftanh(ang.w + bp[3]);                                    \
  float c0, s0, c1, s1, c2, s2, c3, s3;                                     \
  __sincosf(t0, &s0, &c0); __sincosf(t1, &s1, &c1);                         \
  __sincosf(t2, &s2, &c2); __sincosf(t3, &s3, &c3);                         \
  const float g[9] = {1.f, c1, s1, c0, c0 * c1, c0 * s1,                    \
                      s0, s0 * c1, s0 * s1};                                \
  const float h[9] = {1.f, c3, s3, c2, c2 * c3, c2 * s3,                    \
                      s2, s2 * c3, s2 * s3};                                \
  float e0 = 0.f, e1 = 0.f, e2 = 0.f, e3 = 0.f;                             \
  _Pragma("unroll")                                                         \
  for (int p_ = 0; p_ < 9; ++p_) {                                          \
    _Pragma("unroll")                                                       \
    for (int q_ = 0; q_ < 9; ++q_) {                                        \
      const float4 a4 = Aws[p_ * 9 + q_];                                   \
      const float tt = g[p_] * h[q_];                                       \
      e0 = fmaf(a4.x, tt, e0); e1 = fmaf(a4.y, tt, e1);                     \
      e2 = fmaf(a4.z, tt, e2); e3 = fmaf(a4.w, tt, e3);                     \
    }                                                                       \
  }                                                                         \
  reinterpret_cast<float4*>(out)[(R0) + lane] =                             \
      make_float4(e0, e1, e2, e3);                                          \
  asm volatile("" ::: "memory"); }

__global__ __launch_bounds__(256)
__attribute__((amdgpu_waves_per_eu(4, 4)))   // 128-VGPR cap
void qmain_kernel(
    const float* __restrict__ x,     // [B][64]
    const float* __restrict__ Wp,    // [4][64]
    const float* __restrict__ bp,    // [4]
    const float4* __restrict__ Aws,  // [81] float4 (d_ws)
    float* __restrict__ out)         // [B][4]
{
  // per wave: sbuf[2][1024] (8KB, XOR-swizzled) + apatch[256] (1KB)
  __shared__ alignas(16) float lds[4 * 2304];   // 36,864 B -> 4 blocks/CU

  const int tid  = threadIdx.x;
  const int lane = tid & 63;
  const int wid  = tid >> 6;
  const int arow = lane & 15;        // x-row within subtile
  const int kgrp = lane >> 4;        // k-group
  float* sb = &lds[wid * 2304];
  float* ap = sb + 2048;

  const size_t wrow0 = ((size_t)blockIdx.x * 4 + wid) * 128;  // 8 subtiles
  const float4* xs4 = reinterpret_cast<const float4*>(x);

  // write-side swizzle offsets (piece rows: i=0,2 -> lane>>4; i=1,3 -> +4)
  const int wsA = (lane * 4) ^ ((lane >> 4) << 2);
  const int wsB = (lane * 4) ^ (((lane >> 4) + 4) << 2);
  // consume-side swizzle
  const int rw_ = (arow & 7) << 2;
  const int cb_ = arow * 64 + kgrp * 8;

  // B fragment: W^T, cols 0..3 real, 4..15 zero (r13-r19 proven)
  bf16x8 wf0, wf1;
#pragma unroll
  for (int j = 0; j < 8; ++j) {
    if (arow < 4) {
      union { short s; __hip_bfloat16 h; } u0, u1;
      u0.h = __float2bfloat16(Wp[arow * 64 + 0  + kgrp * 8 + j]);
      u1.h = __float2bfloat16(Wp[arow * 64 + 32 + kgrp * 8 + j]);
      wf0[j] = u0.s; wf1[j] = u1.s;
    } else {
      wf0[j] = 0; wf1[j] = 0;
    }
  }
  const f32x4 zero = {0.f, 0.f, 0.f, 0.f};

  const size_t r0 = wrow0;            // tile 0 (subtiles 0-3)
  const size_t r1 = wrow0 + 64;       // tile 1 (subtiles 4-7)

  // 3 transit register sets (48 VGPRs), depth-3 subtiles in flight
  float4 A0, A1, A2, A3, B0, B1, B2, B3, C0, C1, C2, C3;

  ISSUE(0, A0, A1, A2, A3);
  ISSUE(1, B0, B1, B2, B3);
  ISSUE(2, C0, C1, C2, C3);
  WRITE(A0, A1, A2, A3, 0);                              // vmcnt(8)
  WRITE(B0, B1, B2, B3, 1);                              // vmcnt(4)
  CONSUME(0); ISSUE(3, A0, A1, A2, A3); WRITE(C0, C1, C2, C3, 2);
  CONSUME(1); ISSUE(4, B0, B1, B2, B3); WRITE(A0, A1, A2, A3, 3);
  CONSUME(2); ISSUE(5, C0, C1, C2, C3); WRITE(B0, B1, B2, B3, 4);
  CONSUME(3); ISSUE(6, A0, A1, A2, A3); WRITE(C0, C1, C2, C3, 5);

  TAIL(r0);   // subtile 6's loads in flight under the tail

  CONSUME(4); ISSUE(7, B0, B1, B2, B3); WRITE(A0, A1, A2, A3, 6);
  CONSUME(5); WRITE(B0, B1, B2, B3, 7);
  CONSUME(6);
  CONSUME(7);

  TAIL(r1);
}

extern "C" void kernel_launch(void* const* d_in, const int* in_sizes, int n_in,
                              void* d_out, int out_size, void* d_ws, size_t ws_size,
                              hipStream_t stream) {
  const float* x  = (const float*)d_in[0];
  const float* Wp = (const float*)d_in[1];
  const float* bp = (const float*)d_in[2];
  const float* qw = (const float*)d_in[3];
  float* out = (float*)d_out;
  float* A = (float*)d_ws;   // 324 floats
  (void)n_in; (void)out_size; (void)ws_size;

  qprep_kernel<<<1, 256, 0, stream>>>(qw, A);

  const int B = in_sizes[0] / 64;   // 524288 rows
  qmain_kernel<<<B / 512, 256, 0, stream>>>(x, Wp, bp,
                                            (const float4*)A, out);
}